// Round 16
// baseline (53.441 us; speedup 1.0000x reference)
//
#include <hip/hip_runtime.h>
#include <stdint.h>

#define S_TOT 32768
#define MC_DIM 128
#define O_DIM 128
#define BN_EPS 1e-5f
#define S_TILE 128

// ws layout (float units):
#define WS_PART2 0       // [2][32][128] pooled partials (memset 0 each call)
#define WS_FLAGS 8192    // ints: [0]=arrival cnt, [16]=release flag (memset 0 each call)
#define WS_BIAS  12288   // [512] bias2[E=4][O=128]
#define WS_W2    12800   // 32768 float slots = W2 bf16 [E][O][MC] (65536 ushort)

typedef __attribute__((ext_vector_type(8))) short short8;
typedef __attribute__((ext_vector_type(4))) float f32x4;

static __device__ __forceinline__ unsigned short f2bf(float f) {
    union { float f; unsigned int u; } v; v.f = f;
    unsigned int r = v.u + 0x7FFFu + ((v.u >> 16) & 1u);
    return (unsigned short)(r >> 16);
}

// One kernel: stage+pool -> slim fence-free device barrier -> route -> GEMM+epilogue
__global__ __launch_bounds__(256, 2) void k_all(
    const float* __restrict__ f0, const float* __restrict__ f1,
    const float* __restrict__ f2, const float* __restrict__ f3,
    const float* __restrict__ Wc, const float* __restrict__ gamma,
    const float* __restrict__ beta, const float* __restrict__ rmean,
    const float* __restrict__ rvar, const float* __restrict__ Wr,
    const float* __restrict__ br, float* __restrict__ ws,
    float* __restrict__ out) {

    __shared__ uint4 tile4[2048];            // 32 KB swizzled xT tile (verified layout)
    __shared__ float lds_pool[2][128];
    __shared__ float pooled_lds[256];
    char* lds = (char*)tile4;

    int bid = blockIdx.x;                    // 512 = b(2) x st(256); 2 blocks/CU co-resident
    int b = bid >> 8;
    int st = bid & 255;
    int s0 = st * S_TILE;
    int t = threadIdx.x;
    int wv = t >> 6, l = t & 63;

    // ---- distributed W2 = bf16(Wc*inv), bias2: AGENT-scope relaxed atomic stores ----
    // (write-through to the fabric coherence point; no dirty L2 lines, no fence needed — r13-verified)
    if (t < 32) {
        int i = bid * 32 + t;                // 16384 uint2 (8B) total
        int eo = i >> 5;
        float inv = gamma[eo] * rsqrtf(rvar[eo] + BN_EPS);
        float4 w = ((const float4*)Wc)[i];
        unsigned int lo = (unsigned int)f2bf(w.x * inv) | ((unsigned int)f2bf(w.y * inv) << 16);
        unsigned int hi = (unsigned int)f2bf(w.z * inv) | ((unsigned int)f2bf(w.w * inv) << 16);
        unsigned long long pk = (unsigned long long)lo | ((unsigned long long)hi << 32);
        __hip_atomic_store((unsigned long long*)(ws + WS_W2) + i, pk,
                           __ATOMIC_RELAXED, __HIP_MEMORY_SCOPE_AGENT);
    } else if (t == 32) {
        float inv = gamma[bid] * rsqrtf(rvar[bid] + BN_EPS);
        __hip_atomic_store(&ws[WS_BIAS + bid], beta[bid] - rmean[bid] * inv,
                           __ATOMIC_RELAXED, __HIP_MEMORY_SCOPE_AGENT);
    }

    // ---- stage x tile -> LDS + fused pool partials (r7/r8/r13-verified) ----
    // layout: byte(s, c) = s*256 + ((c>>3) ^ (s&15))*16 + (c&7)*2
    #pragma unroll
    for (int m = 0; m < 4; ++m) {
        const float* fp = (m == 0) ? f0 : (m == 1) ? f1 : (m == 2) ? f2 : f3;
        #pragma unroll
        for (int it = 0; it < 4; ++it) {
            int lin = it * 256 + t;          // cql(8) x sl(128)
            int cql = lin >> 7;              // wave-uniform
            int sl = lin & 127;
            const float* src = fp + ((size_t)b * 32 + cql * 4) * S_TOT + s0 + sl;
            float v0 = src[0];
            float v1 = src[S_TOT];
            float v2 = src[2 * (size_t)S_TOT];
            float v3 = src[3 * (size_t)S_TOT];
            int cq = m * 8 + cql;            // global c-quad 0..31
            int gr = cq >> 1, half = cq & 1;
            int gswz = gr ^ (sl & 15);
            int byte = sl * 256 + gswz * 16 + half * 8;
            uint2 pk;
            pk.x = (unsigned int)f2bf(v0) | ((unsigned int)f2bf(v1) << 16);
            pk.y = (unsigned int)f2bf(v2) | ((unsigned int)f2bf(v3) << 16);
            *(uint2*)(lds + byte) = pk;
            float p0 = v0, p1 = v1, p2 = v2, p3 = v3;
            #pragma unroll
            for (int msk = 32; msk >= 1; msk >>= 1) {
                p0 += __shfl_xor(p0, msk);
                p1 += __shfl_xor(p1, msk);
                p2 += __shfl_xor(p2, msk);
                p3 += __shfl_xor(p3, msk);
            }
            if (l == 0) {
                int c = m * 32 + cql * 4;
                lds_pool[wv & 1][c + 0] = p0;
                lds_pool[wv & 1][c + 1] = p1;
                lds_pool[wv & 1][c + 2] = p2;
                lds_pool[wv & 1][c + 3] = p3;
            }
        }
    }
    __syncthreads();

    // ---- fold partials into part2[b][st>>3][c] (device-scope atomicAdd, 8-way contention) ----
    if (t < 128)
        atomicAdd(&ws[WS_PART2 + ((b * 32 + (st >> 3)) * 128) + t], lds_pool[0][t] + lds_pool[1][t]);

    // ---- SLIM fence-free device barrier: 1 arrival RMW + 1 poller per block ----
    {
        int* flags = (int*)ws + WS_FLAGS;    // [0]=cnt, [16]=release (separate lines)
        asm volatile("s_waitcnt vmcnt(0)" ::: "memory");   // this wave's atomics at coherence point
        __syncthreads();                     // all waves drained
        if (t == 0) {
            int old = __hip_atomic_fetch_add(&flags[0], 1,
                                             __ATOMIC_RELAXED, __HIP_MEMORY_SCOPE_AGENT);
            if (old == 511) {
                __hip_atomic_store(&flags[16], 1, __ATOMIC_RELAXED, __HIP_MEMORY_SCOPE_AGENT);
            } else {
                while (__hip_atomic_load(&flags[16], __ATOMIC_RELAXED, __HIP_MEMORY_SCOPE_AGENT) == 0)
                    __builtin_amdgcn_s_sleep(16);   // 512 pollers device-wide: negligible fabric load
            }
        }
        __syncthreads();
        // no fences: all cross-block data is fabric-coherent (atomic writes / atomic reads)
    }

    // ---- pooled reduce via relaxed atomic loads (r13-verified) ----
    {
        int bb = t >> 7, c = t & 127;
        float s = 0.f;
        #pragma unroll
        for (int g = 0; g < 32; ++g)
            s += __hip_atomic_load(&ws[WS_PART2 + ((bb * 32 + g) * 128) + c],
                                   __ATOMIC_RELAXED, __HIP_MEMORY_SCOPE_AGENT);
        pooled_lds[t] = s;
    }
    __syncthreads();

    // ---- all-lane register router (r10/r13-verified) ----
    int e0, e1;
    float w0, w1;
    {
        float lg[8];
        float p0 = pooled_lds[l];
        float p1 = pooled_lds[64 + l];
        float p2 = pooled_lds[128 + l];
        float p3 = pooled_lds[192 + l];
        #pragma unroll
        for (int e = 0; e < 4; ++e) {
            float wc0 = Wr[e * MC_DIM + l];
            float wc1 = Wr[e * MC_DIM + 64 + l];
            lg[e]     = p0 * wc0 + p1 * wc1;
            lg[4 + e] = p2 * wc0 + p3 * wc1;
        }
        #pragma unroll
        for (int msk = 32; msk >= 1; msk >>= 1) {
            #pragma unroll
            for (int e = 0; e < 8; ++e) lg[e] += __shfl_xor(lg[e], msk);
        }
        const float s_inv = 1.0f / (float)S_TOT;
        float probs[2][4];
        int top1[2];
        int ee0[2], ee1[2];
        float vv0[2], vv1[2];
        #pragma unroll
        for (int bb = 0; bb < 2; ++bb) {
            float lo[4];
            #pragma unroll
            for (int e = 0; e < 4; ++e) lo[e] = lg[bb * 4 + e] * s_inv + br[e];
            float mx = fmaxf(fmaxf(lo[0], lo[1]), fmaxf(lo[2], lo[3]));
            float sum = 0.f;
            #pragma unroll
            for (int e = 0; e < 4; ++e) { probs[bb][e] = __expf(lo[e] - mx); sum += probs[bb][e]; }
            float rs = 1.f / sum;
            #pragma unroll
            for (int e = 0; e < 4; ++e) probs[bb][e] *= rs;
            int a0 = 0; float m0 = probs[bb][0];
            #pragma unroll
            for (int e = 1; e < 4; ++e) if (probs[bb][e] > m0) { m0 = probs[bb][e]; a0 = e; }
            int a1 = -1; float m1 = -1.f;
            #pragma unroll
            for (int e = 0; e < 4; ++e) if (e != a0 && probs[bb][e] > m1) { m1 = probs[bb][e]; a1 = e; }
            top1[bb] = a0; ee0[bb] = a0; ee1[bb] = a1; vv0[bb] = m0; vv1[bb] = m1;
        }
        float inv = 1.f / (vv0[b] + vv1[b]);
        e0 = ee0[b]; e1 = ee1[b];
        w0 = vv0[b] * inv; w1 = vv1[b] * inv;
        if (bid == 0 && t == 0) {
            float aux = 0.f;
            #pragma unroll
            for (int e = 0; e < 4; ++e) {
                float fe = 0.5f * ((top1[0] == e) + (top1[1] == e));
                float pe = 0.5f * (probs[0][e] + probs[1][e]);
                aux += fe * pe;
            }
            out[(size_t)8388608] = 4.f * aux;
        }
    }

    const unsigned short* W2 = (const unsigned short*)(ws + WS_W2);
    const float* bias2 = ws + WS_BIAS;

    // ---- dual-expert MFMA GEMM + bias + ReLU + combine (verified) ----
    int o0 = wv * 32;
    int lr = l & 15, lg2 = l >> 4;

    f32x4 acc[2][2][8];
    #pragma unroll
    for (int ee = 0; ee < 2; ++ee)
        #pragma unroll
        for (int of = 0; of < 2; ++of)
            #pragma unroll
            for (int sf = 0; sf < 8; ++sf)
                acc[ee][of][sf] = (f32x4){0.f, 0.f, 0.f, 0.f};

    #pragma unroll
    for (int kk = 0; kk < 4; ++kk) {
        short8 a[2][2];
        #pragma unroll
        for (int ee = 0; ee < 2; ++ee) {
            int e = ee ? e1 : e0;
            #pragma unroll
            for (int of = 0; of < 2; ++of) {
                int o = o0 + of * 16 + lr;   // A: row = lane&15
                a[ee][of] = *(const short8*)(W2 + ((size_t)(e * O_DIM + o) * MC_DIM + kk * 32 + lg2 * 8));
            }
        }
        #pragma unroll
        for (int sf = 0; sf < 8; ++sf) {
            int sl = sf * 16 + lr;           // B: col = lane&15
            int gr = kk * 4 + lg2;
            int byte = sl * 256 + ((gr ^ lr) << 4);
            short8 bb = *(const short8*)(lds + byte);
            #pragma unroll
            for (int ee = 0; ee < 2; ++ee)
                #pragma unroll
                for (int of = 0; of < 2; ++of)
                    acc[ee][of][sf] = __builtin_amdgcn_mfma_f32_16x16x32_bf16(
                        a[ee][of], bb, acc[ee][of][sf], 0, 0, 0);
        }
    }

    #pragma unroll
    for (int of = 0; of < 2; ++of) {
        #pragma unroll
        for (int r = 0; r < 4; ++r) {
            int o = o0 + of * 16 + lg2 * 4 + r;   // C/D: row = (lane>>4)*4 + reg
            float bA = bias2[e0 * O_DIM + o];
            float bB = bias2[e1 * O_DIM + o];
            float* orow = out + ((size_t)(b * O_DIM + o)) * S_TOT + s0;
            #pragma unroll
            for (int sf = 0; sf < 8; ++sf) {
                float y0 = fmaxf(acc[0][of][sf][r] + bA, 0.f);
                float y1 = fmaxf(acc[1][of][sf][r] + bB, 0.f);
                orow[sf * 16 + lr] = w0 * y0 + w1 * y1;
            }
        }
    }
}

extern "C" void kernel_launch(void* const* d_in, const int* in_sizes, int n_in,
                              void* d_out, int out_size, void* d_ws, size_t ws_size,
                              hipStream_t stream) {
    const float* f0    = (const float*)d_in[0];
    const float* f1    = (const float*)d_in[1];
    const float* f2    = (const float*)d_in[2];
    const float* f3    = (const float*)d_in[3];
    const float* Wc    = (const float*)d_in[4];
    const float* gamma = (const float*)d_in[5];
    const float* beta  = (const float*)d_in[6];
    const float* rmean = (const float*)d_in[7];
    const float* rvar  = (const float*)d_in[8];
    const float* Wr    = (const float*)d_in[9];
    const float* br    = (const float*)d_in[10];
    float* ws  = (float*)d_ws;
    float* out = (float*)d_out;

    // zero part2 + cnt/flag (deterministic across graph replays)
    hipMemsetAsync(d_ws, 0, (8192 + 4096) * sizeof(float), stream);
    hipLaunchKernelGGL(k_all, dim3(512), dim3(256), 0, stream,
                       f0, f1, f2, f3, Wc, gamma, beta, rmean, rvar, Wr, br, ws, out);
}

// Round 17
// 27.945 us; speedup vs baseline: 1.9124x; 1.9124x over previous
//
#include <hip/hip_runtime.h>
#include <stdint.h>

#define S_TOT 32768
#define MC_DIM 128
#define O_DIM 128
#define BN_EPS 1e-5f
#define S_TILE 128

// ws layout (float units):
#define WS_PART  0        // [256] pooled channel sums [b=2][c=128]
#define WS_BIAS  512      // [512] bias2[E=4][O=128]
#define WS_W2    1024     // 32768 float slots = W2 bf16 [E][O][MC] (65536 ushort)

typedef __attribute__((ext_vector_type(8))) short short8;
typedef __attribute__((ext_vector_type(4))) float f32x4;

static __device__ __forceinline__ unsigned short f2bf(float f) {
    union { float f; unsigned int u; } v; v.f = f;
    unsigned int r = v.u + 0x7FFFu + ((v.u >> 16) & 1u);
    return (unsigned short)(r >> 16);
}

// ---------------- K1: pooled sums (1 channel/block) + W2 fold  [r10-verified, 27.96us config] ----------------
__global__ __launch_bounds__(256) void k_pool(
    const float* __restrict__ f0, const float* __restrict__ f1,
    const float* __restrict__ f2, const float* __restrict__ f3,
    const float* __restrict__ Wc, const float* __restrict__ gamma,
    const float* __restrict__ beta, const float* __restrict__ rmean,
    const float* __restrict__ rvar, float* __restrict__ ws) {

    __shared__ float red[4];
    int bid = blockIdx.x;                    // 256 = b(2) x c(128)
    int b = bid >> 7, c = bid & 127;
    int t = threadIdx.x;
    int wv = t >> 6, l = t & 63;

    // distributed W2 = bf16(Wc*inv): 16384 quads / 256 blocks = 64 each
    if (t < 64) {
        int i = bid * 64 + t;
        int eo = i >> 5;
        float inv = gamma[eo] * rsqrtf(rvar[eo] + BN_EPS);
        float4 w = ((const float4*)Wc)[i];
        uint2 pk;
        pk.x = (unsigned int)f2bf(w.x * inv) | ((unsigned int)f2bf(w.y * inv) << 16);
        pk.y = (unsigned int)f2bf(w.z * inv) | ((unsigned int)f2bf(w.w * inv) << 16);
        ((uint2*)(ws + WS_W2))[i] = pk;
    } else if (t < 66) {
        int i = bid * 2 + (t - 64);          // 512 bias entries / 256 blocks = 2 each
        float inv = gamma[i] * rsqrtf(rvar[i] + BN_EPS);
        ws[WS_BIAS + i] = beta[i] - rmean[i] * inv;
    }

    const float* fp = (c < 32) ? f0 : (c < 64) ? f1 : (c < 96) ? f2 : f3;
    const float4* base = (const float4*)(fp + ((size_t)b * 32 + (c & 31)) * S_TOT);
    float s = 0.f;
    #pragma unroll
    for (int j = 0; j < 32; ++j) {           // 256 thr * 32 * 4 = 32768 floats
        float4 v = base[j * 256 + t];
        s += (v.x + v.y) + (v.z + v.w);
    }
    #pragma unroll
    for (int msk = 32; msk >= 1; msk >>= 1) s += __shfl_xor(s, msk);
    if (l == 0) red[wv] = s;
    __syncthreads();
    if (t == 0) ws[WS_PART + bid] = (red[0] + red[1]) + (red[2] + red[3]);
}

// ---------------- K2: all-lane register router + stage + dual-expert GEMM ----------------
__global__ __launch_bounds__(256, 2) void k_moe(
    const float* __restrict__ f0, const float* __restrict__ f1,
    const float* __restrict__ f2, const float* __restrict__ f3,
    const float* __restrict__ Wr, const float* __restrict__ br,
    const float* __restrict__ ws, float* __restrict__ out) {

    __shared__ uint4 tile4[2048];            // 32 KB swizzled xT tile (verified layout)
    char* lds = (char*)tile4;

    int bid = blockIdx.x;                    // 512 = b(2) x st(256)
    int b = bid >> 8;
    int st = bid & 255;
    int s0 = st * S_TILE;
    int t = threadIdx.x;
    int wv = t >> 6, l = t & 63;

    // ---- all-lane register router (every wave redundant; no LDS, no sync, no serial lane) ----
    float lg[8];
    {
        float p0 = ws[WS_PART + l];          // pooled sums b=0
        float p1 = ws[WS_PART + 64 + l];
        float p2 = ws[WS_PART + 128 + l];    // b=1
        float p3 = ws[WS_PART + 192 + l];
        #pragma unroll
        for (int e = 0; e < 4; ++e) {
            float wc0 = Wr[e * MC_DIM + l];
            float wc1 = Wr[e * MC_DIM + 64 + l];
            lg[e]     = p0 * wc0 + p1 * wc1;
            lg[4 + e] = p2 * wc0 + p3 * wc1;
        }
        #pragma unroll
        for (int msk = 32; msk >= 1; msk >>= 1) {
            #pragma unroll
            for (int e = 0; e < 8; ++e) lg[e] += __shfl_xor(lg[e], msk);
        }
        // butterfly leaves full sums in EVERY lane
    }
    int e0, e1;
    float w0, w1;
    {
        const float s_inv = 1.0f / (float)S_TOT;
        float probs[2][4];
        int top1[2];
        int ee0[2], ee1[2];
        float vv0[2], vv1[2];
        #pragma unroll
        for (int bb = 0; bb < 2; ++bb) {
            float lo[4];
            #pragma unroll
            for (int e = 0; e < 4; ++e) lo[e] = lg[bb * 4 + e] * s_inv + br[e];
            float mx = fmaxf(fmaxf(lo[0], lo[1]), fmaxf(lo[2], lo[3]));
            float sum = 0.f;
            #pragma unroll
            for (int e = 0; e < 4; ++e) { probs[bb][e] = __expf(lo[e] - mx); sum += probs[bb][e]; }
            float rs = 1.f / sum;
            #pragma unroll
            for (int e = 0; e < 4; ++e) probs[bb][e] *= rs;
            int a0 = 0; float m0 = probs[bb][0];
            #pragma unroll
            for (int e = 1; e < 4; ++e) if (probs[bb][e] > m0) { m0 = probs[bb][e]; a0 = e; }
            int a1 = -1; float m1 = -1.f;
            #pragma unroll
            for (int e = 0; e < 4; ++e) if (e != a0 && probs[bb][e] > m1) { m1 = probs[bb][e]; a1 = e; }
            top1[bb] = a0; ee0[bb] = a0; ee1[bb] = a1; vv0[bb] = m0; vv1[bb] = m1;
        }
        float inv = 1.f / (vv0[b] + vv1[b]);
        e0 = ee0[b]; e1 = ee1[b];
        w0 = vv0[b] * inv; w1 = vv1[b] * inv;
        if (bid == 0 && t == 0) {
            float aux = 0.f;
            #pragma unroll
            for (int e = 0; e < 4; ++e) {
                float fe = 0.5f * ((top1[0] == e) + (top1[1] == e));
                float pe = 0.5f * (probs[0][e] + probs[1][e]);
                aux += fe * pe;
            }
            out[(size_t)8388608] = 4.f * aux;
        }
    }

    // ---- stage x tile -> LDS (r8-verified: coalesced dword loads, uint2 writes) ----
    // layout: byte(s, c) = s*256 + ((c>>3) ^ (s&15))*16 + (c&7)*2
    #pragma unroll
    for (int m = 0; m < 4; ++m) {
        const float* fp = (m == 0) ? f0 : (m == 1) ? f1 : (m == 2) ? f2 : f3;
        #pragma unroll
        for (int it = 0; it < 4; ++it) {
            int lin = it * 256 + t;          // cql(8) x sl(128)
            int cql = lin >> 7;              // wave-uniform
            int sl = lin & 127;
            const float* src = fp + ((size_t)b * 32 + cql * 4) * S_TOT + s0 + sl;
            float v0 = src[0];
            float v1 = src[S_TOT];
            float v2 = src[2 * (size_t)S_TOT];
            float v3 = src[3 * (size_t)S_TOT];
            int cq = m * 8 + cql;            // global c-quad 0..31
            int gr = cq >> 1, half = cq & 1;
            int gswz = gr ^ (sl & 15);
            int byte = sl * 256 + gswz * 16 + half * 8;
            uint2 pk;
            pk.x = (unsigned int)f2bf(v0) | ((unsigned int)f2bf(v1) << 16);
            pk.y = (unsigned int)f2bf(v2) | ((unsigned int)f2bf(v3) << 16);
            *(uint2*)(lds + byte) = pk;
        }
    }
    __syncthreads();                          // tile ready

    const unsigned short* W2 = (const unsigned short*)(ws + WS_W2);
    const float* bias2 = ws + WS_BIAS;

    // ---- dual-expert MFMA GEMM + bias + ReLU + combine (verified r8/r10) ----
    int o0 = wv * 32;
    int lr = l & 15, lg2 = l >> 4;

    f32x4 acc[2][2][8];
    #pragma unroll
    for (int ee = 0; ee < 2; ++ee)
        #pragma unroll
        for (int of = 0; of < 2; ++of)
            #pragma unroll
            for (int sf = 0; sf < 8; ++sf)
                acc[ee][of][sf] = (f32x4){0.f, 0.f, 0.f, 0.f};

    #pragma unroll
    for (int kk = 0; kk < 4; ++kk) {
        short8 a[2][2];
        #pragma unroll
        for (int ee = 0; ee < 2; ++ee) {
            int e = ee ? e1 : e0;
            #pragma unroll
            for (int of = 0; of < 2; ++of) {
                int o = o0 + of * 16 + lr;   // A: row = lane&15
                a[ee][of] = *(const short8*)(W2 + ((size_t)(e * O_DIM + o) * MC_DIM + kk * 32 + lg2 * 8));
            }
        }
        #pragma unroll
        for (int sf = 0; sf < 8; ++sf) {
            int sl = sf * 16 + lr;           // B: col = lane&15
            int gr = kk * 4 + lg2;
            int byte = sl * 256 + ((gr ^ lr) << 4);
            short8 bb = *(const short8*)(lds + byte);
            #pragma unroll
            for (int ee = 0; ee < 2; ++ee)
                #pragma unroll
                for (int of = 0; of < 2; ++of)
                    acc[ee][of][sf] = __builtin_amdgcn_mfma_f32_16x16x32_bf16(
                        a[ee][of], bb, acc[ee][of][sf], 0, 0, 0);
        }
    }

    #pragma unroll
    for (int of = 0; of < 2; ++of) {
        #pragma unroll
        for (int r = 0; r < 4; ++r) {
            int o = o0 + of * 16 + lg2 * 4 + r;   // C/D: row = (lane>>4)*4 + reg
            float bA = bias2[e0 * O_DIM + o];
            float bB = bias2[e1 * O_DIM + o];
            float* orow = out + ((size_t)(b * O_DIM + o)) * S_TOT + s0;
            #pragma unroll
            for (int sf = 0; sf < 8; ++sf) {
                float y0 = fmaxf(acc[0][of][sf][r] + bA, 0.f);
                float y1 = fmaxf(acc[1][of][sf][r] + bB, 0.f);
                orow[sf * 16 + lr] = w0 * y0 + w1 * y1;
            }
        }
    }
}

extern "C" void kernel_launch(void* const* d_in, const int* in_sizes, int n_in,
                              void* d_out, int out_size, void* d_ws, size_t ws_size,
                              hipStream_t stream) {
    const float* f0    = (const float*)d_in[0];
    const float* f1    = (const float*)d_in[1];
    const float* f2    = (const float*)d_in[2];
    const float* f3    = (const float*)d_in[3];
    const float* Wc    = (const float*)d_in[4];
    const float* gamma = (const float*)d_in[5];
    const float* beta  = (const float*)d_in[6];
    const float* rmean = (const float*)d_in[7];
    const float* rvar  = (const float*)d_in[8];
    const float* Wr    = (const float*)d_in[9];
    const float* br    = (const float*)d_in[10];
    float* ws  = (float*)d_ws;
    float* out = (float*)d_out;

    hipLaunchKernelGGL(k_pool, dim3(256), dim3(256), 0, stream,
                       f0, f1, f2, f3, Wc, gamma, beta, rmean, rvar, ws);
    hipLaunchKernelGGL(k_moe, dim3(512), dim3(256), 0, stream,
                       f0, f1, f2, f3, Wr, br, ws, out);
}